// Round 5
// baseline (110.587 us; speedup 1.0000x reference)
//
#include <hip/hip_runtime.h>
#include <cmath>

#define N_NODES 1500
#define NBLK    512
#define NTHR    256

// bf16 helpers (bf16 <-> f32 are pure bit ops)
__device__ __forceinline__ float blo(unsigned u) {
    union { unsigned i; float f; } v; v.i = u << 16; return v.f;
}
__device__ __forceinline__ float bhi(unsigned u) {
    union { unsigned i; float f; } v; v.i = u & 0xffff0000u; return v.f;
}
__device__ __forceinline__ ushort f2bf(float f) {
    union { float f; unsigned u; } v; v.f = f;
    return (ushort)((v.u + 0x7fffu + ((v.u >> 16) & 1u)) >> 16);  // RNE
}

// Fused kernel, ONE plain launch.
// Phase 1: htab[i][k] = bf16(h1[i,k]+b1[k]), htab[i][64+k] = bf16(h2[i,k]).
//   Block b covers rows {b, b+512, b+1024}; 128 threads per row (64 cols x 2
//   halves), two rows in flight per step.
// Manual grid barrier (counter in ws, zeroed by a memset node each call;
// __launch_bounds__(256,2) guarantees >=2 blocks/CU -> 512 blocks co-resident).
// Phase 2: 8 edges per wave, 4 grid-stride jobs per wave (R3-verified math).
__global__ __launch_bounds__(NTHR, 2)
void pg_fused(const float* __restrict__ embed,
              const float* __restrict__ W1,
              const float* __restrict__ b1,
              const int* __restrict__ e0,
              const int* __restrict__ e1,
              const float* __restrict__ noise,
              const float* __restrict__ tmp_p,
              const float* __restrict__ W2,
              const float* __restrict__ b2,
              unsigned* __restrict__ ctr,
              ushort* __restrict__ htab,
              float* __restrict__ out,
              int E) {
    const int t = threadIdx.x;
    const int b = blockIdx.x;

    // ---------------- Phase 1: h tables ----------------
    {
        const int slot = t >> 7;          // 0/1: which of 2 concurrent rows
        const int tt   = t & 127;
        const int k    = tt & 63;
        const int half = tt >> 6;

        __shared__ float emb_s[2][64];

        const float* wcol = W1 + (half << 6) * 64 + k;   // column k of W1 half
        const float bias  = (half == 0) ? b1[k] : 0.0f;

#pragma unroll
        for (int step = 0; step < 2; ++step) {
            const int r = b + (step * 2 + slot) * NBLK;  // b, b+512 | b+1024, b+1536
            if (step) __syncthreads();                   // protect emb_s reuse
            if (r < N_NODES && tt < 64) emb_s[slot][tt] = embed[r * 64 + tt];
            __syncthreads();
            if (r < N_NODES) {
                float a0 = bias, a1 = 0.0f, a2 = 0.0f, a3 = 0.0f;
#pragma unroll
                for (int f = 0; f < 64; f += 4) {
                    a0 = fmaf(emb_s[slot][f + 0], wcol[(f + 0) * 64], a0);
                    a1 = fmaf(emb_s[slot][f + 1], wcol[(f + 1) * 64], a1);
                    a2 = fmaf(emb_s[slot][f + 2], wcol[(f + 2) * 64], a2);
                    a3 = fmaf(emb_s[slot][f + 3], wcol[(f + 3) * 64], a3);
                }
                htab[r * 128 + half * 64 + k] = f2bf((a0 + a1) + (a2 + a3));
            }
        }
    }

    // ---------------- Manual grid barrier ----------------
    __threadfence();                 // release htab stores device-wide
    __syncthreads();
    if (t == 0) {
        atomicAdd(ctr, 1u);          // device-scope by default
        while (atomicAdd(ctr, 0u) < (unsigned)NBLK) {
            __builtin_amdgcn_s_sleep(2);
        }
    }
    __syncthreads();
    __threadfence();                 // acquire side

    // ---------------- Phase 2: edges ----------------
    const int wave = (b << 2) + (t >> 6);   // 0..2047
    const int lane = t & 63;
    const int g    = lane >> 3;             // edge slot within wave
    const int l    = lane & 7;              // bf16x8 chunk within node row

    const float bb    = b2[0];
    const float inv_t = 1.0f / tmp_p[0];
    const float4 w2a = ((const float4*)W2)[l * 2];
    const float4 w2b = ((const float4*)W2)[l * 2 + 1];

    for (int j = 0; (j * 2048 + wave) * 8 < E; ++j) {
        const int e      = (j * 2048 + wave) * 8 + g;
        const bool valid = (e < E);
        const int ee     = valid ? e : 0;

        const int r = e0[ee];
        const int c = e1[ee];

        // noise gather early: lane 0 fwd (r,c), lane 1 rev (c,r)
        float nv = 0.5f;
        if (l < 2) nv = noise[(l == 0) ? (r * N_NODES + c) : (c * N_NODES + r)];

        const uint4* hr = (const uint4*)(htab + r * 128);
        const uint4* hc = (const uint4*)(htab + c * 128);
        const uint4 h1r = hr[l];
        const uint4 h2r = hr[l + 8];
        const uint4 h1c = hc[l];
        const uint4 h2c = hc[l + 8];

        float p = fmaxf(blo(h1r.x) + blo(h2c.x), 0.0f) * w2a.x;
        p = fmaf(fmaxf(bhi(h1r.x) + bhi(h2c.x), 0.0f), w2a.y, p);
        p = fmaf(fmaxf(blo(h1r.y) + blo(h2c.y), 0.0f), w2a.z, p);
        p = fmaf(fmaxf(bhi(h1r.y) + bhi(h2c.y), 0.0f), w2a.w, p);
        p = fmaf(fmaxf(blo(h1r.z) + blo(h2c.z), 0.0f), w2b.x, p);
        p = fmaf(fmaxf(bhi(h1r.z) + bhi(h2c.z), 0.0f), w2b.y, p);
        p = fmaf(fmaxf(blo(h1r.w) + blo(h2c.w), 0.0f), w2b.z, p);
        p = fmaf(fmaxf(bhi(h1r.w) + bhi(h2c.w), 0.0f), w2b.w, p);

        float s = fmaxf(blo(h1c.x) + blo(h2r.x), 0.0f) * w2a.x;
        s = fmaf(fmaxf(bhi(h1c.x) + bhi(h2r.x), 0.0f), w2a.y, s);
        s = fmaf(fmaxf(blo(h1c.y) + blo(h2r.y), 0.0f), w2a.z, s);
        s = fmaf(fmaxf(bhi(h1c.y) + bhi(h2r.y), 0.0f), w2a.w, s);
        s = fmaf(fmaxf(blo(h1c.z) + blo(h2r.z), 0.0f), w2b.x, s);
        s = fmaf(fmaxf(bhi(h1c.z) + bhi(h2r.z), 0.0f), w2b.y, s);
        s = fmaf(fmaxf(blo(h1c.w) + blo(h2r.w), 0.0f), w2b.z, s);
        s = fmaf(fmaxf(bhi(h1c.w) + bhi(h2r.w), 0.0f), w2b.w, s);

        // combined reduction: parity swap folds p/s in one shuffle, then xor 2,4
        const bool odd = (l & 1);
        float w = odd ? s : p;
        float z = odd ? p : s;
        w += __shfl_xor(z, 1, 64);
        w += __shfl_xor(w, 2, 64);
        w += __shfl_xor(w, 4, 64);
        // l==0: fwd sum, l==1: rev sum

        float gate = 0.0f;
        if (l < 2) {
            const float x = (__logf(nv / (1.0f - nv)) + w + bb) * inv_t;
            gate = 1.0f / (1.0f + __expf(-x));
        }
        const float gother = __shfl_xor(gate, 1, 64);
        if (valid && l == 0) out[e] = 0.5f * (gate + gother);
    }
}

extern "C" void kernel_launch(void* const* d_in, const int* in_sizes, int n_in,
                              void* d_out, int out_size, void* d_ws, size_t ws_size,
                              hipStream_t stream) {
    const float* embed = (const float*)d_in[0];
    const int*   eidx  = (const int*)d_in[1];
    const float* noise = (const float*)d_in[2];
    const float* tmp_p = (const float*)d_in[3];
    const float* W1    = (const float*)d_in[4];
    const float* b1    = (const float*)d_in[5];
    const float* W2    = (const float*)d_in[6];
    const float* b2    = (const float*)d_in[7];
    float* out = (float*)d_out;

    const int E = in_sizes[1] / 2;           // edge_index is [2, E]
    const int* e0 = eidx;
    const int* e1 = eidx + E;

    // ws layout: [0,4)   barrier counter (zeroed every call)
    //            [128,.) htab: [N_NODES][128] bf16 (16B-aligned)
    unsigned* ctr  = (unsigned*)d_ws;
    ushort*   htab = (ushort*)((char*)d_ws + 128);

    hipMemsetAsync(ctr, 0, 4, stream);

    pg_fused<<<NBLK, NTHR, 0, stream>>>(embed, W1, b1, e0, e1, noise,
                                        tmp_p, W2, b2, ctr, htab, out, E);
}